// Round 1
// baseline (125.746 us; speedup 1.0000x reference)
//
#include <hip/hip_runtime.h>
#include <math.h>

#define MAXB 32
#define CCH 85

// ---------------------------------------------------------------------------
// Kernel 1: collect all target boxes with obj>0 per (layer, image).
// Reference's top_k(32) + (vals>0) mask is exactly equivalent to gathering all
// obj>0 boxes (count <= 20 by construction), since zero-val boxes contribute
// iou=0. Order within the set doesn't matter (max is commutative).
// ---------------------------------------------------------------------------
__global__ void collect_boxes(const float* __restrict__ t0,
                              const float* __restrict__ t1,
                              const float* __restrict__ t2,
                              float* __restrict__ boxes,
                              int* __restrict__ counts) {
    int lb = blockIdx.x;          // 0..47
    int l  = lb >> 4;             // layer
    int b  = lb & 15;             // image
    const float* T;
    int g;
    if (l == 0)      { T = t0; g = 13; }
    else if (l == 1) { T = t1; g = 26; }
    else             { T = t2; g = 52; }
    int cells = g * g * 3;
    const float* tb = T + (size_t)b * cells * CCH;
    for (int c = threadIdx.x; c < cells; c += blockDim.x) {
        float obj = tb[(size_t)c * CCH + 4];
        if (obj > 0.0f) {
            int pos = atomicAdd(&counts[lb], 1);
            if (pos < MAXB) {
                float* dst = boxes + ((size_t)lb * MAXB + pos) * 4;
                dst[0] = tb[(size_t)c * CCH + 0];
                dst[1] = tb[(size_t)c * CCH + 1];
                dst[2] = tb[(size_t)c * CCH + 2];
                dst[3] = tb[(size_t)c * CCH + 3];
            }
        }
    }
}

// ---------------------------------------------------------------------------
// Kernel 2: per-cell loss. One thread per (layer,b,h,w,a) cell.
// obj==0 path (99.5% of cells): reads pred[0..4] + tgt[4] only; conf-BCE
// gated by IoU-ignore. obj==1 path: full 85-channel loss; ignore factor is
// irrelevant there since (obj + (1-obj)*ignore) == 1.
// ---------------------------------------------------------------------------
__global__ void yolo_loss(const float* __restrict__ p0, const float* __restrict__ t0,
                          const float* __restrict__ p1, const float* __restrict__ t1,
                          const float* __restrict__ p2, const float* __restrict__ t2,
                          const float* __restrict__ anchors,
                          const float* __restrict__ boxes,
                          const int* __restrict__ counts,
                          float* __restrict__ out) {
    const int n0 = 16 * 13 * 13 * 3;   // 8112
    const int n1 = 16 * 26 * 26 * 3;   // 32448
    const int n2 = 16 * 52 * 52 * 3;   // 129792
    int i = blockIdx.x * blockDim.x + threadIdx.x;
    float loss = 0.0f;
    if (i < n0 + n1 + n2) {
        int l, li, g;
        const float *P, *T;
        if (i < n0)           { l = 0; li = i;           g = 13; P = p0; T = t0; }
        else if (i < n0 + n1) { l = 1; li = i - n0;      g = 26; P = p1; T = t1; }
        else                  { l = 2; li = i - n0 - n1; g = 52; P = p2; T = t2; }
        int cpi = g * g * 3;
        int b = li / cpi;
        int c = li % cpi;
        int a = c % 3;
        int w = (c / 3) % g;
        int h = c / (3 * g);
        size_t base = (size_t)li * CCH;

        float px = P[base + 0], py = P[base + 1];
        float pw = P[base + 2], ph = P[base + 3];
        float pc = P[base + 4];
        float obj = T[base + 4];

        float ancx = anchors[((2 - l) * 3 + a) * 2 + 0];
        float ancy = anchors[((2 - l) * 3 + a) * 2 + 1];
        float gf = (float)g;

        if (obj > 0.0f) {
            float tx = T[base + 0], ty = T[base + 1];
            float tw = T[base + 2], th = T[base + 3];
            float scale = 2.0f - tw * th;
            float rtx = tx * gf - (float)w;
            float rty = ty * gf - (float)h;
            float twx = tw * 416.0f / ancx;
            float twy = th * 416.0f / ancy;
            float rtw = (twx != 0.0f) ? logf(twx) : 0.0f;
            float rth = (twy != 0.0f) ? logf(twy) : 0.0f;
            // xy BCE * scale (obj==1)
            loss += (-(rtx * logf(px) + (1.0f - rtx) * log1pf(-px))) * scale;
            loss += (-(rty * logf(py) + (1.0f - rty) * log1pf(-py))) * scale;
            // wh 0.5*MSE * scale
            loss += 0.5f * (pw - rtw) * (pw - rtw) * scale;
            loss += 0.5f * (ph - rth) * (ph - rth) * scale;
            // conf BCE with t=1, factor (obj + (1-obj)*ignore) == 1
            loss += -logf(pc);
            // cls BCE
            for (int k = 5; k < CCH; ++k) {
                float pk = P[base + k], tk = T[base + k];
                loss += -(tk * logf(pk) + (1.0f - tk) * log1pf(-pk));
            }
        } else {
            // ignore mask from max IoU vs this image's target boxes
            float pxn = (px + (float)w) / gf;
            float pyn = (py + (float)h) / gf;
            float pwn = expf(pw) * ancx / 416.0f;
            float phn = expf(ph) * ancy / 416.0f;
            float pl = pxn - pwn * 0.5f, pr = pxn + pwn * 0.5f;
            float pt = pyn - phn * 0.5f, pb = pyn + phn * 0.5f;
            float p_area = pwn * phn;
            int lb = l * 16 + b;
            int cnt = counts[lb];
            if (cnt > MAXB) cnt = MAXB;
            const float* bx = boxes + (size_t)lb * MAXB * 4;
            float maxiou = 0.0f;
            for (int k = 0; k < cnt; ++k) {
                float txc = bx[k * 4 + 0], tyc = bx[k * 4 + 1];
                float twc = bx[k * 4 + 2], thc = bx[k * 4 + 3];
                float il = fmaxf(pl, txc - twc * 0.5f);
                float ir = fminf(pr, txc + twc * 0.5f);
                float it = fmaxf(pt, tyc - thc * 0.5f);
                float ib = fminf(pb, tyc + thc * 0.5f);
                float iw = fmaxf(ir - il, 0.0f);
                float ih = fmaxf(ib - it, 0.0f);
                float inter = iw * ih;
                float iou = inter / (p_area + twc * thc - inter);
                maxiou = fmaxf(maxiou, iou);
            }
            float ignore = (maxiou < 0.5f) ? 1.0f : 0.0f;
            loss += (-log1pf(-pc)) * ignore;
        }
    }

    // mean over batch == sum/16
    loss *= (1.0f / 16.0f);

    // wave (64) shuffle reduce, then cross-wave via LDS
    for (int off = 32; off > 0; off >>= 1)
        loss += __shfl_down(loss, off, 64);
    __shared__ float s[4];
    int lane = threadIdx.x & 63, wid = threadIdx.x >> 6;
    if (lane == 0) s[wid] = loss;
    __syncthreads();
    if (threadIdx.x == 0) {
        atomicAdd(out, s[0] + s[1] + s[2] + s[3]);
    }
}

extern "C" void kernel_launch(void* const* d_in, const int* in_sizes, int n_in,
                              void* d_out, int out_size, void* d_ws, size_t ws_size,
                              hipStream_t stream) {
    const float* p0 = (const float*)d_in[0];
    const float* t0 = (const float*)d_in[1];
    const float* p1 = (const float*)d_in[2];
    const float* t1 = (const float*)d_in[3];
    const float* p2 = (const float*)d_in[4];
    const float* t2 = (const float*)d_in[5];
    const float* anchors = (const float*)d_in[6];

    int*   counts = (int*)d_ws;                    // 48 ints
    float* boxes  = (float*)((char*)d_ws + 256);   // 48*32*4 floats

    // fresh state every call (harness does not re-poison between replays)
    hipMemsetAsync(d_ws, 0, 256, stream);
    hipMemsetAsync(d_out, 0, sizeof(float), stream);

    collect_boxes<<<48, 256, 0, stream>>>(t0, t1, t2, boxes, counts);

    const int total = 16 * (13 * 13 + 26 * 26 + 52 * 52) * 3;  // 170352
    int blocks = (total + 255) / 256;
    yolo_loss<<<blocks, 256, 0, stream>>>(p0, t0, p1, t1, p2, t2,
                                          anchors, boxes, counts, (float*)d_out);
}

// Round 3
// 59.243 us; speedup vs baseline: 2.1225x; 2.1225x over previous
//
#include <hip/hip_runtime.h>
#include <math.h>

#define MAXB 32
#define CCH  85
#define N0   (16*13*13*3)   // 8112
#define N1   (16*26*26*3)   // 32448
#define N2   (16*52*52*3)   // 129792
#define NTOT (N0+N1+N2)     // 170352

// d_ws layout:
//   [0,192)     counts[48]        (int)
//   [192,196)   nentries          (int)
//   [256,24832) boxes[48][32][4]  (float, 16B-aligned entries)
//   [25088,...) entries[960]      (int)

__device__ __forceinline__ void decode(int i, int& l, int& li, int& g,
                                       const float*& P, const float*& T,
                                       const float* p0, const float* t0,
                                       const float* p1, const float* t1,
                                       const float* p2, const float* t2) {
    if (i < N0)           { l = 0; li = i;           g = 13; P = p0; T = t0; }
    else if (i < N0 + N1) { l = 1; li = i - N0;      g = 26; P = p1; T = t1; }
    else                  { l = 2; li = i - N0 - N1; g = 52; P = p2; T = t2; }
}

// ---------------------------------------------------------------------------
// Kernel 1: one thread per cell; collect obj>0 boxes per (layer,image) and a
// global entry list for the dense obj-loss kernel. top_k(32)+(vals>0) mask in
// the reference is exactly "the set of obj>0 boxes" (count <= 20 < 32), and
// set-max IoU is order-independent, so atomic append order doesn't matter.
// ---------------------------------------------------------------------------
__global__ void collect_boxes(const float* __restrict__ t0,
                              const float* __restrict__ t1,
                              const float* __restrict__ t2,
                              float* __restrict__ boxes,
                              int* __restrict__ counts,
                              int* __restrict__ nentries,
                              int* __restrict__ entries) {
    int i = blockIdx.x * blockDim.x + threadIdx.x;
    if (i >= NTOT) return;
    int l, li, g;
    const float* P = nullptr;
    const float* T = nullptr;
    decode(i, l, li, g, P, T, t0, t0, t1, t1, t2, t2);
    size_t base = (size_t)li * CCH;
    float obj = T[base + 4];
    if (obj > 0.0f) {
        int cpi = g * g * 3;
        int b = li / cpi;
        int lb = l * 16 + b;
        int pos = atomicAdd(&counts[lb], 1);
        if (pos < MAXB) {
            float* dst = boxes + ((size_t)lb * MAXB + pos) * 4;
            dst[0] = T[base + 0];
            dst[1] = T[base + 1];
            dst[2] = T[base + 2];
            dst[3] = T[base + 3];
        }
        int e = atomicAdd(nentries, 1);
        entries[e] = (l << 20) | li;
    }
}

// ---------------------------------------------------------------------------
// Kernel 2: conf loss for EVERY cell (uniform, ~1 transcendental/thread).
//   obj==1: -log(pc)               (factor obj+(1-obj)*ignore == 1)
//   obj==0: -log(1-pc) * ignore    (ignore from max-IoU vs target boxes)
// xy/wh/cls terms for obj cells live in obj_loss (kernel 3).
// ---------------------------------------------------------------------------
__global__ void conf_loss(const float* __restrict__ p0, const float* __restrict__ t0,
                          const float* __restrict__ p1, const float* __restrict__ t1,
                          const float* __restrict__ p2, const float* __restrict__ t2,
                          const float* __restrict__ anchors,
                          const float* __restrict__ boxes,
                          const int* __restrict__ counts,
                          float* __restrict__ out) {
    int i = blockIdx.x * blockDim.x + threadIdx.x;
    float loss = 0.0f;
    if (i < NTOT) {
        int l, li, g;
        const float* P = nullptr;
        const float* T = nullptr;
        decode(i, l, li, g, P, T, p0, t0, p1, t1, p2, t2);
        int cpi = g * g * 3;
        int b = li / cpi;
        int c = li % cpi;
        int a = c % 3;
        int w = (c / 3) % g;
        int h = c / (3 * g);
        size_t base = (size_t)li * CCH;

        float px = P[base + 0], py = P[base + 1];
        float pw = P[base + 2], ph = P[base + 3];
        float pc = P[base + 4];
        float obj = T[base + 4];

        if (obj > 0.0f) {
            loss = -__logf(pc);
        } else {
            float ancx = anchors[((2 - l) * 3 + a) * 2 + 0];
            float ancy = anchors[((2 - l) * 3 + a) * 2 + 1];
            float gf = (float)g;
            float pxn = (px + (float)w) / gf;
            float pyn = (py + (float)h) / gf;
            float pwn = __expf(pw) * ancx * (1.0f / 416.0f);
            float phn = __expf(ph) * ancy * (1.0f / 416.0f);
            float pl = pxn - pwn * 0.5f, pr = pxn + pwn * 0.5f;
            float pt = pyn - phn * 0.5f, pb = pyn + phn * 0.5f;
            float p_area = pwn * phn;
            int lb = l * 16 + b;
            int cnt = counts[lb];
            if (cnt > MAXB) cnt = MAXB;
            const float4* bx = (const float4*)(boxes + (size_t)lb * MAXB * 4);
            float maxiou = 0.0f;
            #pragma unroll 4
            for (int k = 0; k < cnt; ++k) {
                float4 tb = bx[k];
                float il = fmaxf(pl, tb.x - tb.z * 0.5f);
                float ir = fminf(pr, tb.x + tb.z * 0.5f);
                float it = fmaxf(pt, tb.y - tb.w * 0.5f);
                float ib = fminf(pb, tb.y + tb.w * 0.5f);
                float iw = fmaxf(ir - il, 0.0f);
                float ih = fmaxf(ib - it, 0.0f);
                float inter = iw * ih;
                float iou = __fdividef(inter, p_area + tb.z * tb.w - inter);
                maxiou = fmaxf(maxiou, iou);
            }
            loss = (maxiou < 0.5f) ? -__logf(1.0f - pc) : 0.0f;
        }
    }

    loss *= (1.0f / 16.0f);   // mean over batch == sum/16

    for (int off = 32; off > 0; off >>= 1)
        loss += __shfl_down(loss, off, 64);
    __shared__ float s[4];
    int lane = threadIdx.x & 63, wid = threadIdx.x >> 6;
    if (lane == 0) s[wid] = loss;
    __syncthreads();
    if (threadIdx.x == 0)
        atomicAdd(out, s[0] + s[1] + s[2] + s[3]);
}

// ---------------------------------------------------------------------------
// Kernel 3: one wave per obj cell. Lane-parallel coalesced load of the full
// 85-channel P and T rows; lane-parallel cls BCE; lane 0 adds xy/wh terms.
// ---------------------------------------------------------------------------
__global__ void obj_loss(const float* __restrict__ p0, const float* __restrict__ t0,
                         const float* __restrict__ p1, const float* __restrict__ t1,
                         const float* __restrict__ p2, const float* __restrict__ t2,
                         const float* __restrict__ anchors,
                         const int* __restrict__ entries,
                         const int* __restrict__ nentries,
                         float* __restrict__ out) {
    int total = *nentries;
    int e = blockIdx.x;
    if (e >= total) return;
    int enc = entries[e];
    int l = enc >> 20, li = enc & 0xFFFFF;
    const float *P, *T; int g;
    if (l == 0)      { g = 13; P = p0; T = t0; }
    else if (l == 1) { g = 26; P = p1; T = t1; }
    else             { g = 52; P = p2; T = t2; }
    int cpi = g * g * 3;
    int c = li % cpi;
    int a = c % 3;
    int w = (c / 3) % g;
    int h = c / (3 * g);
    size_t base = (size_t)li * CCH;

    int lane = threadIdx.x;                       // 0..63
    float pv = P[base + lane];
    float tv = T[base + lane];
    bool has2 = lane < (CCH - 64);                // lanes 0..20 -> ch 64..84
    float pv2 = 1.0f, tv2 = 1.0f;
    if (has2) { pv2 = P[base + 64 + lane]; tv2 = T[base + 64 + lane]; }

    float tx = __shfl(tv, 0, 64), ty = __shfl(tv, 1, 64);
    float tw = __shfl(tv, 2, 64), th = __shfl(tv, 3, 64);
    float px = __shfl(pv, 0, 64), py = __shfl(pv, 1, 64);
    float pw = __shfl(pv, 2, 64), ph = __shfl(pv, 3, 64);

    float partial = 0.0f;
    if (lane >= 5)
        partial += -(tv * __logf(pv) + (1.0f - tv) * __logf(1.0f - pv));
    if (has2)
        partial += -(tv2 * __logf(pv2) + (1.0f - tv2) * __logf(1.0f - pv2));

    if (lane == 0) {
        float scale = 2.0f - tw * th;
        float gf = (float)g;
        float rtx = tx * gf - (float)w;
        float rty = ty * gf - (float)h;
        float ancx = anchors[((2 - l) * 3 + a) * 2 + 0];
        float ancy = anchors[((2 - l) * 3 + a) * 2 + 1];
        float rtw = __logf(tw * 416.0f / ancx);   // tw,th > 0 at obj cells
        float rth = __logf(th * 416.0f / ancy);
        partial += (-(rtx * __logf(px) + (1.0f - rtx) * __logf(1.0f - px))) * scale;
        partial += (-(rty * __logf(py) + (1.0f - rty) * __logf(1.0f - py))) * scale;
        partial += 0.5f * (pw - rtw) * (pw - rtw) * scale;
        partial += 0.5f * (ph - rth) * (ph - rth) * scale;
    }

    for (int off = 32; off > 0; off >>= 1)
        partial += __shfl_down(partial, off, 64);
    if (lane == 0)
        atomicAdd(out, partial * (1.0f / 16.0f));
}

extern "C" void kernel_launch(void* const* d_in, const int* in_sizes, int n_in,
                              void* d_out, int out_size, void* d_ws, size_t ws_size,
                              hipStream_t stream) {
    const float* p0 = (const float*)d_in[0];
    const float* t0 = (const float*)d_in[1];
    const float* p1 = (const float*)d_in[2];
    const float* t1 = (const float*)d_in[3];
    const float* p2 = (const float*)d_in[4];
    const float* t2 = (const float*)d_in[5];
    const float* anchors = (const float*)d_in[6];

    int*   counts   = (int*)d_ws;
    int*   nentries = (int*)((char*)d_ws + 192);
    float* boxes    = (float*)((char*)d_ws + 256);
    int*   entries  = (int*)((char*)d_ws + 25088);

    (void)hipMemsetAsync(d_ws, 0, 256, stream);         // counts + nentries
    (void)hipMemsetAsync(d_out, 0, sizeof(float), stream);

    const int blocks = (NTOT + 255) / 256;              // 666
    collect_boxes<<<blocks, 256, 0, stream>>>(t0, t1, t2, boxes, counts,
                                              nentries, entries);
    conf_loss<<<blocks, 256, 0, stream>>>(p0, t0, p1, t1, p2, t2,
                                          anchors, boxes, counts, (float*)d_out);
    obj_loss<<<960, 64, 0, stream>>>(p0, t0, p1, t1, p2, t2,
                                     anchors, entries, nentries, (float*)d_out);
}